// Round 18
// baseline (56.524 us; speedup 1.0000x reference)
//
#include <hip/hip_runtime.h>
#include <hip/hip_bf16.h>

typedef __bf16 bf16x8 __attribute__((ext_vector_type(8)));
typedef __bf16 bf16x4 __attribute__((ext_vector_type(4)));
typedef float  f32x4  __attribute__((ext_vector_type(4)));
typedef float  flt4v  __attribute__((ext_vector_type(4)));
typedef int    int4v  __attribute__((ext_vector_type(4)));

#define ALPHA 0.2f
#define LOG2E 1.44269504089f
// B=8, N=2048, D=128. Inputs: h,W,a f32; adj int32. Output f32.
// Wh stored MFMA-B-fragment-native: T[b][jt(32)][kk(2)][ct(8)][lane(64)][u(8)] bf16.

// Kernel A: Wh + scores (unchanged from round 17).
__global__ __launch_bounds__(256) void gat_wh(
    const float* __restrict__ h,
    const float* __restrict__ W,
    const float* __restrict__ a,
    __bf16* __restrict__ T,                  // [8][262144] bf16 tiled Wh
    float* __restrict__ ssrc,                // [8*2048] (x log2e)
    float* __restrict__ sdst)                // [8*2048] (x log2e)
{
    __shared__ __bf16 Wt[128][136];
    __shared__ float wvs[128], wvd[128];
    const int tid = threadIdx.x;
    if (tid < 128) {
        float s0 = 0.f, s1 = 0.f;
        const float* wr = W + tid * 128;
        #pragma unroll 4
        for (int e = 0; e < 128; ++e) {
            float w = wr[e];
            s0 += w * a[e];
            s1 += w * a[128 + e];
        }
        wvs[tid] = s0; wvd[tid] = s1;
    }
    #pragma unroll
    for (int it = 0; it < 8; ++it) {
        int o = (it * 256 + tid) * 8;
        flt4v v0 = *reinterpret_cast<const flt4v*>(W + o);
        flt4v v1 = *reinterpret_cast<const flt4v*>(W + o + 4);
        int d = o >> 7, e = o & 127;
        #pragma unroll
        for (int j = 0; j < 4; ++j) {
            Wt[e + j][d]     = (__bf16)v0[j];
            Wt[e + 4 + j][d] = (__bf16)v1[j];
        }
    }
    __syncthreads();
    const int wave = tid >> 6, lane = tid & 63;
    const int lr = lane & 15, lg = lane >> 4;
    const int row0 = blockIdx.x * 64 + wave * 16;
    f32x4 acc[8];
    #pragma unroll
    for (int ct = 0; ct < 8; ++ct) acc[ct] = (f32x4){0.f, 0.f, 0.f, 0.f};
    #pragma unroll
    for (int kk = 0; kk < 4; ++kk) {
        const float* hp = h + (size_t)(row0 + lr) * 128 + kk * 32 + lg * 8;
        flt4v h0 = *reinterpret_cast<const flt4v*>(hp);
        flt4v h1 = *reinterpret_cast<const flt4v*>(hp + 4);
        bf16x8 af;
        #pragma unroll
        for (int j = 0; j < 4; ++j) { af[j] = (__bf16)h0[j]; af[4 + j] = (__bf16)h1[j]; }
        #pragma unroll
        for (int ct = 0; ct < 8; ++ct) {
            bf16x8 bf_ = *reinterpret_cast<const bf16x8*>(&Wt[ct * 16 + lr][kk * 32 + lg * 8]);
            acc[ct] = __builtin_amdgcn_mfma_f32_16x16x32_bf16(af, bf_, acc[ct], 0, 0, 0);
        }
    }
    const int b  = row0 >> 11;
    const int n0 = row0 & 2047;
    __bf16* tb = T + (size_t)b * 262144;
    const int j0t = n0 + lg * 4;
    const int jt  = j0t >> 6;
    const int kk2 = (j0t >> 5) & 1;
    const int lgp = (j0t >> 3) & 3;
    const int u0  = j0t & 7;
    #pragma unroll
    for (int ct = 0; ct < 8; ++ct) {
        bf16x4 v;
        #pragma unroll
        for (int q = 0; q < 4; ++q) v[q] = (__bf16)acc[ct][q];
        *reinterpret_cast<bf16x4*>(tb + ((jt * 2 + kk2) * 8 + ct) * 512 + lgp * 128 + lr * 8 + u0) = v;
    }
    const float* hrow = h + (size_t)(row0 + lr) * 128 + lg * 32;
    float s0 = 0.f, s1 = 0.f;
    #pragma unroll
    for (int u = 0; u < 32; u += 4) {
        flt4v hv = *reinterpret_cast<const flt4v*>(hrow + u);
        #pragma unroll
        for (int q = 0; q < 4; ++q) {
            float x = hv[q];
            s0 += x * wvs[lg * 32 + u + q];
            s1 += x * wvd[lg * 32 + u + q];
        }
    }
    s0 += __shfl_xor(s0, 16, 64); s0 += __shfl_xor(s0, 32, 64);
    s1 += __shfl_xor(s1, 16, 64); s1 += __shfl_xor(s1, 32, 64);
    if (lg == 0) {
        ssrc[row0 + lr] = s0 * LOG2E;
        sdst[row0 + lr] = s1 * LOG2E;
    }
}

// Kernel C: 16-ROW TILES, 1024 blocks (4 blocks/CU -> up to 32 waves/CU).
// Block: 512 thr = 8 waves. P-role: wave w owns rows 2w,2w+1; lane l: row=2w+(l>>5),
// j-chunk=(l&31)*4 (32 lanes x 4 j = 512B contiguous adj/sdst reads). P written
// bf16x4 into A-frag-native LDS. MFMA-role: wave w = (t2=w>>2, kk=(w>>1)&1, cp=w&1)
// owns 4 ct tiles; no B-frag loaded twice. Merge: 4 sequential adds into accsh.
__global__ __launch_bounds__(512) void gat_attn(
    const int* __restrict__ adj,                // [8][2048][2048]
    const __bf16* __restrict__ T,               // [8][262144] bf16 tiled Wh
    const float* __restrict__ ssrc,             // x log2e
    const float* __restrict__ sdst,             // x log2e
    float* __restrict__ out)                    // [8][2048][128] f32
{
    __shared__ __bf16 Pl[2][4][512];            // [dbuf][t2*2+kk][lane*8+u] (8 KB)
    __shared__ float accsh[16][132];            // merge buffer (8.4 KB)
    __shared__ float lsumf[16];

    const int tid = threadIdx.x, w = tid >> 6, l = tid & 63;
    const int b  = blockIdx.x & 7;
    const int i0 = (blockIdx.x >> 3) << 4;      // 16-row tile base

    // ---- P-role geometry ----
    const int prow = 2 * w + (l >> 5);          // row within 16-tile
    const int row  = i0 + prow;
    const int l5   = l & 31;
    const int jc   = l5 * 4;                    // j-chunk within 128-j interval
    const int pbuf  = (l5 >> 4) * 2 + ((l5 >> 3) & 1);
    const int palane = prow + ((l5 & 7) >> 1) * 16;
    const int pu0   = (l5 & 1) * 4;
    const float si = ssrc[b * 2048 + row];
    const int* arow = adj + ((size_t)b * 2048 + row) * 2048;
    const float* sd = sdst + b * 2048;
    const __bf16* tb = T + (size_t)b * 262144;

    // ---- MFMA-role geometry ----
    const int t2w = w >> 2, kkw = (w >> 1) & 1, cp = w & 1;

    f32x4 acc[4];
    #pragma unroll
    for (int c = 0; c < 4; ++c) acc[c] = (f32x4){0.f, 0.f, 0.f, 0.f};
    float lrow = 0.f;

    // ---- prologue: P(interval 0) ----
    {
        int4v a0 = *reinterpret_cast<const int4v*>(arow + jc);
        flt4v s0 = *reinterpret_cast<const flt4v*>(sd + jc);
        bf16x4 pw;
        #pragma unroll
        for (int u = 0; u < 4; ++u) {
            float e = si + s0[u];
            e = fmaxf(e, ALPHA * e);
            float p = exp2f(e);
            p = (a0[u] != 0) ? p : 0.f;
            __bf16 pb = (__bf16)p;
            lrow += (float)pb;
            pw[u] = pb;
        }
        *reinterpret_cast<bf16x4*>(&Pl[0][pbuf][palane * 8 + pu0]) = pw;
    }
    __syncthreads();

    // ---- pipelined main loop ----
    #pragma unroll 2
    for (int iv = 0; iv < 16; ++iv) {
        const int cur = iv & 1, nxt = cur ^ 1;
        const int jt = iv * 2 + t2w;
        // (1) prefetch next-interval P inputs
        int4v an = {0, 0, 0, 0};
        flt4v sn;
        if (iv < 15) {
            const int off = (iv + 1) * 128 + jc;
            an = *reinterpret_cast<const int4v*>(arow + off);
            sn = *reinterpret_cast<const flt4v*>(sd + off);
        }
        // (2) B-frag loads (4 ct tiles, coalesced 1KB/instr)
        const __bf16* tk = tb + (size_t)(((jt * 2 + kkw) * 8) + cp * 4) * 512 + l * 8;
        bf16x8 bf0 = *reinterpret_cast<const bf16x8*>(tk);
        bf16x8 bf1 = *reinterpret_cast<const bf16x8*>(tk + 512);
        bf16x8 bf2 = *reinterpret_cast<const bf16x8*>(tk + 1024);
        bf16x8 bf3 = *reinterpret_cast<const bf16x8*>(tk + 1536);
        // (3) A-frag LDS read (one per wave, reused 4x)
        bf16x8 af = *reinterpret_cast<const bf16x8*>(&Pl[cur][t2w * 2 + kkw][l * 8]);
        // (4) MFMAs
        acc[0] = __builtin_amdgcn_mfma_f32_16x16x32_bf16(af, bf0, acc[0], 0, 0, 0);
        acc[1] = __builtin_amdgcn_mfma_f32_16x16x32_bf16(af, bf1, acc[1], 0, 0, 0);
        acc[2] = __builtin_amdgcn_mfma_f32_16x16x32_bf16(af, bf2, acc[2], 0, 0, 0);
        acc[3] = __builtin_amdgcn_mfma_f32_16x16x32_bf16(af, bf3, acc[3], 0, 0, 0);
        // (5) exp + ds_write next-P
        if (iv < 15) {
            bf16x4 pw;
            #pragma unroll
            for (int u = 0; u < 4; ++u) {
                float e = si + sn[u];
                e = fmaxf(e, ALPHA * e);
                float p = exp2f(e);
                p = (an[u] != 0) ? p : 0.f;
                __bf16 pb = (__bf16)p;
                lrow += (float)pb;
                pw[u] = pb;
            }
            *reinterpret_cast<bf16x4*>(&Pl[nxt][pbuf][palane * 8 + pu0]) = pw;
        }
        // (6) barrier
        __syncthreads();
    }

    // ---- denominators: 32 lanes per row ----
    lrow += __shfl_xor(lrow, 1, 64);
    lrow += __shfl_xor(lrow, 2, 64);
    lrow += __shfl_xor(lrow, 4, 64);
    lrow += __shfl_xor(lrow, 8, 64);
    lrow += __shfl_xor(lrow, 16, 64);
    if (l5 == 0) lsumf[prow] = lrow;

    // ---- merge: 4 sequential (t2,kk) groups; cp pair writes disjoint cols ----
    #pragma unroll
    for (int s = 0; s < 4; ++s) {
        if ((w >> 1) == s) {
            #pragma unroll
            for (int c = 0; c < 4; ++c) {
                const int col = (cp * 4 + c) * 16 + (l & 15);
                #pragma unroll
                for (int q = 0; q < 4; ++q) {
                    const int r = (l >> 4) * 4 + q;
                    if (s == 0) accsh[r][col] = acc[c][q];
                    else        accsh[r][col] += acc[c][q];
                }
            }
        }
        __syncthreads();
    }

    // ---- write out: thread t -> row t>>5, cols (t&31)*4 ----
    const int r  = tid >> 5;
    const int c0 = (tid & 31) * 4;
    const float den = lsumf[r];
    flt4v o;
    #pragma unroll
    for (int u = 0; u < 4; ++u) o[u] = accsh[r][c0 + u] / den;
    *reinterpret_cast<flt4v*>(out + ((size_t)b * 2048 + i0 + r) * 128 + c0) = o;
}

extern "C" void kernel_launch(void* const* d_in, const int* in_sizes, int n_in,
                              void* d_out, int out_size, void* d_ws, size_t ws_size,
                              hipStream_t stream)
{
    const float* h = nullptr; const int* adj = nullptr;
    const float* W = nullptr; const float* a = nullptr;
    for (int i = 0; i < n_in; ++i) {
        switch (in_sizes[i]) {
            case 2097152:  h   = (const float*)d_in[i]; break;
            case 33554432: adj = (const int*)d_in[i];   break;
            case 16384:    W   = (const float*)d_in[i]; break;
            case 256:      a   = (const float*)d_in[i]; break;
        }
    }
    if (!h || !adj || !W || !a) {
        h   = (const float*)d_in[0];
        adj = (const int*)d_in[1];
        W   = (const float*)d_in[2];
        a   = (const float*)d_in[3];
    }

    __bf16* T = (__bf16*)d_ws;                                        // 4 MB
    float* ssrc = (float*)((char*)d_ws + (size_t)4 * 1024 * 1024);    // 64 KB
    float* sdst = ssrc + 8 * 2048;                                    // 64 KB

    gat_wh<<<256, 256, 0, stream>>>(h, W, a, T, ssrc, sdst);
    gat_attn<<<1024, 512, 0, stream>>>(adj, T, ssrc, sdst, (float*)d_out);
}

// Round 19
// 52.156 us; speedup vs baseline: 1.0837x; 1.0837x over previous
//
#include <hip/hip_runtime.h>
#include <hip/hip_bf16.h>

typedef __bf16 bf16x8 __attribute__((ext_vector_type(8)));
typedef __bf16 bf16x4 __attribute__((ext_vector_type(4)));
typedef float  f32x4  __attribute__((ext_vector_type(4)));
typedef float  flt4v  __attribute__((ext_vector_type(4)));
typedef int    int4v  __attribute__((ext_vector_type(4)));

#define ALPHA 0.2f
#define LOG2E 1.44269504089f
// B=8, N=2048, D=128. Inputs: h,W,a f32; adj int32. Output f32.
// Wh stored MFMA-B-fragment-native: T[b][jt(32)][kk(2)][ct(8)][lane(64)][u(8)] bf16.

// Kernel A: Wh + scores (unchanged round-17 version).
__global__ __launch_bounds__(256) void gat_wh(
    const float* __restrict__ h,
    const float* __restrict__ W,
    const float* __restrict__ a,
    __bf16* __restrict__ T,                  // [8][262144] bf16 tiled Wh
    float* __restrict__ ssrc,                // [8*2048] (x log2e)
    float* __restrict__ sdst)                // [8*2048] (x log2e)
{
    __shared__ __bf16 Wt[128][136];
    __shared__ float wvs[128], wvd[128];
    const int tid = threadIdx.x;
    if (tid < 128) {
        float s0 = 0.f, s1 = 0.f;
        const float* wr = W + tid * 128;
        #pragma unroll 4
        for (int e = 0; e < 128; ++e) {
            float w = wr[e];
            s0 += w * a[e];
            s1 += w * a[128 + e];
        }
        wvs[tid] = s0; wvd[tid] = s1;
    }
    #pragma unroll
    for (int it = 0; it < 8; ++it) {
        int o = (it * 256 + tid) * 8;
        flt4v v0 = *reinterpret_cast<const flt4v*>(W + o);
        flt4v v1 = *reinterpret_cast<const flt4v*>(W + o + 4);
        int d = o >> 7, e = o & 127;
        #pragma unroll
        for (int j = 0; j < 4; ++j) {
            Wt[e + j][d]     = (__bf16)v0[j];
            Wt[e + 4 + j][d] = (__bf16)v1[j];
        }
    }
    __syncthreads();
    const int wave = tid >> 6, lane = tid & 63;
    const int lr = lane & 15, lg = lane >> 4;
    const int row0 = blockIdx.x * 64 + wave * 16;
    f32x4 acc[8];
    #pragma unroll
    for (int ct = 0; ct < 8; ++ct) acc[ct] = (f32x4){0.f, 0.f, 0.f, 0.f};
    #pragma unroll
    for (int kk = 0; kk < 4; ++kk) {
        const float* hp = h + (size_t)(row0 + lr) * 128 + kk * 32 + lg * 8;
        flt4v h0 = *reinterpret_cast<const flt4v*>(hp);
        flt4v h1 = *reinterpret_cast<const flt4v*>(hp + 4);
        bf16x8 af;
        #pragma unroll
        for (int j = 0; j < 4; ++j) { af[j] = (__bf16)h0[j]; af[4 + j] = (__bf16)h1[j]; }
        #pragma unroll
        for (int ct = 0; ct < 8; ++ct) {
            bf16x8 bf_ = *reinterpret_cast<const bf16x8*>(&Wt[ct * 16 + lr][kk * 32 + lg * 8]);
            acc[ct] = __builtin_amdgcn_mfma_f32_16x16x32_bf16(af, bf_, acc[ct], 0, 0, 0);
        }
    }
    const int b  = row0 >> 11;
    const int n0 = row0 & 2047;
    __bf16* tb = T + (size_t)b * 262144;
    const int j0t = n0 + lg * 4;
    const int jt  = j0t >> 6;
    const int kk2 = (j0t >> 5) & 1;
    const int lgp = (j0t >> 3) & 3;
    const int u0  = j0t & 7;
    #pragma unroll
    for (int ct = 0; ct < 8; ++ct) {
        bf16x4 v;
        #pragma unroll
        for (int q = 0; q < 4; ++q) v[q] = (__bf16)acc[ct][q];
        *reinterpret_cast<bf16x4*>(tb + ((jt * 2 + kk2) * 8 + ct) * 512 + lgp * 128 + lr * 8 + u0) = v;
    }
    const float* hrow = h + (size_t)(row0 + lr) * 128 + lg * 32;
    float s0 = 0.f, s1 = 0.f;
    #pragma unroll
    for (int u = 0; u < 32; u += 4) {
        flt4v hv = *reinterpret_cast<const flt4v*>(hrow + u);
        #pragma unroll
        for (int q = 0; q < 4; ++q) {
            float x = hv[q];
            s0 += x * wvs[lg * 32 + u + q];
            s1 += x * wvd[lg * 32 + u + q];
        }
    }
    s0 += __shfl_xor(s0, 16, 64); s0 += __shfl_xor(s0, 32, 64);
    s1 += __shfl_xor(s1, 16, 64); s1 += __shfl_xor(s1, 32, 64);
    if (lg == 0) {
        ssrc[row0 + lr] = s0 * LOG2E;
        sdst[row0 + lr] = s1 * LOG2E;
    }
}

// Kernel C (round-17 structure + DEEPER PREFETCH): 32-row tiles, 512 blocks,
// 512 thr = 8 waves. adj/sdst prefetched 2 intervals deep (regs), B-frags 1 deep.
__global__ __launch_bounds__(512) void gat_attn(
    const int* __restrict__ adj,                // [8][2048][2048]
    const __bf16* __restrict__ T,               // [8][262144] bf16 tiled Wh
    const float* __restrict__ ssrc,             // x log2e
    const float* __restrict__ sdst,             // x log2e
    float* __restrict__ out)                    // [8][2048][128] f32
{
    __shared__ __bf16 Pl[2][8][512];            // double-buffered A-frag P (16 KB)
    __shared__ float  lsumf[32];
    __shared__ f32x4  mbuf[4][2][2][64];        // kk=1 partial accs (16 KB)

    const int tid = threadIdx.x, w = tid >> 6, l = tid & 63;
    const int lr = l & 15, lg = l >> 4;
    const int kkR = w >> 2, cp = w & 3;         // MFMA-role
    const int b  = blockIdx.x & 7;
    const int i0 = (blockIdx.x >> 3) << 5;

    // P-role geometry (identical to round 17)
    const int prow = 4 * w + (l >> 4);
    const int row  = i0 + prow;
    const int jc   = (l & 15) * 8;
    const int pt2  = (l & 15) >> 3;
    const int pkk  = ((l & 15) >> 2) & 1;
    const int plgp = (l & 15) & 3;
    const int pbuf = pt2 * 4 + (w >> 2) * 2 + pkk;
    const int pslot = (prow & 15) + plgp * 16;
    const float si = ssrc[b * 2048 + row];
    const int* arow = adj + ((size_t)b * 2048 + row) * 2048;
    const float* sd = sdst + b * 2048;
    const __bf16* tb = T + (size_t)b * 262144;

    f32x4 acc[2][2];
    #pragma unroll
    for (int g = 0; g < 2; ++g)
        #pragma unroll
        for (int c2 = 0; c2 < 2; ++c2) acc[g][c2] = (f32x4){0.f, 0.f, 0.f, 0.f};
    float lrow = 0.f;

    // ---- prologue: P(interval 0) -> Pl[0] ----
    {
        int4v a0 = *reinterpret_cast<const int4v*>(arow + jc);
        int4v a1 = *reinterpret_cast<const int4v*>(arow + jc + 4);
        flt4v s0 = *reinterpret_cast<const flt4v*>(sd + jc);
        flt4v s1 = *reinterpret_cast<const flt4v*>(sd + jc + 4);
        bf16x8 pw;
        #pragma unroll
        for (int u = 0; u < 4; ++u) {
            float e0 = si + s0[u], e1 = si + s1[u];
            e0 = fmaxf(e0, ALPHA * e0); e1 = fmaxf(e1, ALPHA * e1);
            float p0 = exp2f(e0), p1 = exp2f(e1);
            p0 = (a0[u] != 0) ? p0 : 0.f;
            p1 = (a1[u] != 0) ? p1 : 0.f;
            __bf16 pb0 = (__bf16)p0, pb1 = (__bf16)p1;
            lrow += (float)pb0 + (float)pb1;
            pw[u] = pb0; pw[4 + u] = pb1;
        }
        *reinterpret_cast<bf16x8*>(&Pl[0][pbuf][pslot * 8]) = pw;
    }
    // ---- prefetch adj/sdst: interval 1 -> A regs, interval 2 -> B regs ----
    int4v aA0, aA1, aB0, aB1;
    flt4v sA0, sA1, sB0, sB1;
    {
        const int o1 = 128 + jc, o2 = 256 + jc;
        aA0 = *reinterpret_cast<const int4v*>(arow + o1);
        aA1 = *reinterpret_cast<const int4v*>(arow + o1 + 4);
        sA0 = *reinterpret_cast<const flt4v*>(sd + o1);
        sA1 = *reinterpret_cast<const flt4v*>(sd + o1 + 4);
        aB0 = *reinterpret_cast<const int4v*>(arow + o2);
        aB1 = *reinterpret_cast<const int4v*>(arow + o2 + 4);
        sB0 = *reinterpret_cast<const flt4v*>(sd + o2);
        sB1 = *reinterpret_cast<const flt4v*>(sd + o2 + 4);
    }
    // ---- prefetch B-frags for interval 0 ----
    bf16x8 Bc00, Bc01, Bc10, Bc11;
    {
        const __bf16* tk0 = tb + (size_t)(((0 * 2 + kkR) * 8) + cp * 2) * 512 + l * 8;
        const __bf16* tk1 = tb + (size_t)(((1 * 2 + kkR) * 8) + cp * 2) * 512 + l * 8;
        Bc00 = *reinterpret_cast<const bf16x8*>(tk0);
        Bc01 = *reinterpret_cast<const bf16x8*>(tk0 + 512);
        Bc10 = *reinterpret_cast<const bf16x8*>(tk1);
        Bc11 = *reinterpret_cast<const bf16x8*>(tk1 + 512);
    }
    __syncthreads();

    // ---- pipelined main loop: one barrier per interval ----
    #pragma unroll 2
    for (int iv = 0; iv < 16; ++iv) {
        const int cur = iv & 1, nxt = cur ^ 1;
        // (1) B-frag prefetch for iv+1
        bf16x8 Bn00, Bn01, Bn10, Bn11;
        if (iv < 15) {
            const int jt0 = (iv + 1) * 2;
            const __bf16* tk0 = tb + (size_t)(((jt0 * 2 + kkR) * 8) + cp * 2) * 512 + l * 8;
            const __bf16* tk1 = tb + (size_t)((((jt0 + 1) * 2 + kkR) * 8) + cp * 2) * 512 + l * 8;
            Bn00 = *reinterpret_cast<const bf16x8*>(tk0);
            Bn01 = *reinterpret_cast<const bf16x8*>(tk0 + 512);
            Bn10 = *reinterpret_cast<const bf16x8*>(tk1);
            Bn11 = *reinterpret_cast<const bf16x8*>(tk1 + 512);
        }
        // (2) A-frag LDS reads
        bf16x8 a00 = *reinterpret_cast<const bf16x8*>(&Pl[cur][0 + 0 + kkR][l * 8]);
        bf16x8 a01 = *reinterpret_cast<const bf16x8*>(&Pl[cur][0 + 2 + kkR][l * 8]);
        bf16x8 a10 = *reinterpret_cast<const bf16x8*>(&Pl[cur][4 + 0 + kkR][l * 8]);
        bf16x8 a11 = *reinterpret_cast<const bf16x8*>(&Pl[cur][4 + 2 + kkR][l * 8]);
        // (3) MFMAs on current B regs (loaded one interval ago)
        acc[0][0] = __builtin_amdgcn_mfma_f32_16x16x32_bf16(a00, Bc00, acc[0][0], 0, 0, 0);
        acc[0][1] = __builtin_amdgcn_mfma_f32_16x16x32_bf16(a00, Bc01, acc[0][1], 0, 0, 0);
        acc[1][0] = __builtin_amdgcn_mfma_f32_16x16x32_bf16(a01, Bc00, acc[1][0], 0, 0, 0);
        acc[1][1] = __builtin_amdgcn_mfma_f32_16x16x32_bf16(a01, Bc01, acc[1][1], 0, 0, 0);
        acc[0][0] = __builtin_amdgcn_mfma_f32_16x16x32_bf16(a10, Bc10, acc[0][0], 0, 0, 0);
        acc[0][1] = __builtin_amdgcn_mfma_f32_16x16x32_bf16(a10, Bc11, acc[0][1], 0, 0, 0);
        acc[1][0] = __builtin_amdgcn_mfma_f32_16x16x32_bf16(a11, Bc10, acc[1][0], 0, 0, 0);
        acc[1][1] = __builtin_amdgcn_mfma_f32_16x16x32_bf16(a11, Bc11, acc[1][1], 0, 0, 0);
        // (4) exp + ds_write P(iv+1) from A regs (loaded ~2 intervals ago)
        if (iv < 15) {
            bf16x8 pw;
            #pragma unroll
            for (int u = 0; u < 4; ++u) {
                float e0 = si + sA0[u], e1 = si + sA1[u];
                e0 = fmaxf(e0, ALPHA * e0); e1 = fmaxf(e1, ALPHA * e1);
                float p0 = exp2f(e0), p1 = exp2f(e1);
                p0 = (aA0[u] != 0) ? p0 : 0.f;
                p1 = (aA1[u] != 0) ? p1 : 0.f;
                __bf16 pb0 = (__bf16)p0, pb1 = (__bf16)p1;
                lrow += (float)pb0 + (float)pb1;
                pw[u] = pb0; pw[4 + u] = pb1;
            }
            *reinterpret_cast<bf16x8*>(&Pl[nxt][pbuf][pslot * 8]) = pw;
        }
        // (5) rotate adj regs; refill B-slot with interval iv+3
        if (iv < 14) {
            aA0 = aB0; aA1 = aB1; sA0 = sB0; sA1 = sB1;
        }
        if (iv < 13) {
            const int off = (iv + 3) * 128 + jc;
            aB0 = *reinterpret_cast<const int4v*>(arow + off);
            aB1 = *reinterpret_cast<const int4v*>(arow + off + 4);
            sB0 = *reinterpret_cast<const flt4v*>(sd + off);
            sB1 = *reinterpret_cast<const flt4v*>(sd + off + 4);
        }
        // (6) barrier
        __syncthreads();
        // (7) rotate B regs
        if (iv < 15) { Bc00 = Bn00; Bc01 = Bn01; Bc10 = Bn10; Bc11 = Bn11; }
    }

    // denominators: each row owned by one 16-lane group
    lrow += __shfl_xor(lrow, 1, 64);
    lrow += __shfl_xor(lrow, 2, 64);
    lrow += __shfl_xor(lrow, 4, 64);
    lrow += __shfl_xor(lrow, 8, 64);
    if ((l & 15) == 0) lsumf[prow] = lrow;
    // kk=1 waves publish their partial accumulators
    if (kkR == 1) {
        #pragma unroll
        for (int g = 0; g < 2; ++g)
            #pragma unroll
            for (int c2 = 0; c2 < 2; ++c2)
                mbuf[cp][g][c2][l] = acc[g][c2];
    }
    __syncthreads();
    // kk=0 waves merge + write output
    if (kkR == 0) {
        #pragma unroll
        for (int g = 0; g < 2; ++g) {
            float den[4];
            #pragma unroll
            for (int q = 0; q < 4; ++q) den[q] = lsumf[g * 16 + lg * 4 + q];
            #pragma unroll
            for (int c2 = 0; c2 < 2; ++c2) {
                f32x4 av = acc[g][c2];
                f32x4 mv = mbuf[cp][g][c2][l];
                const int col = (cp * 2 + c2) * 16 + lr;
                #pragma unroll
                for (int q = 0; q < 4; ++q) {
                    const int orow = i0 + g * 16 + lg * 4 + q;
                    out[((size_t)b * 2048 + orow) * 128 + col] = (av[q] + mv[q]) / den[q];
                }
            }
        }
    }
}

extern "C" void kernel_launch(void* const* d_in, const int* in_sizes, int n_in,
                              void* d_out, int out_size, void* d_ws, size_t ws_size,
                              hipStream_t stream)
{
    const float* h = nullptr; const int* adj = nullptr;
    const float* W = nullptr; const float* a = nullptr;
    for (int i = 0; i < n_in; ++i) {
        switch (in_sizes[i]) {
            case 2097152:  h   = (const float*)d_in[i]; break;
            case 33554432: adj = (const int*)d_in[i];   break;
            case 16384:    W   = (const float*)d_in[i]; break;
            case 256:      a   = (const float*)d_in[i]; break;
        }
    }
    if (!h || !adj || !W || !a) {
        h   = (const float*)d_in[0];
        adj = (const int*)d_in[1];
        W   = (const float*)d_in[2];
        a   = (const float*)d_in[3];
    }

    __bf16* T = (__bf16*)d_ws;                                        // 4 MB
    float* ssrc = (float*)((char*)d_ws + (size_t)4 * 1024 * 1024);    // 64 KB
    float* sdst = ssrc + 8 * 2048;                                    // 64 KB

    gat_wh<<<256, 256, 0, stream>>>(h, W, a, T, ssrc, sdst);
    gat_attn<<<512, 512, 0, stream>>>(adj, T, ssrc, sdst, (float*)d_out);
}

// Round 20
// 49.449 us; speedup vs baseline: 1.1431x; 1.0548x over previous
//
#include <hip/hip_runtime.h>
#include <hip/hip_bf16.h>

typedef __bf16 bf16x8 __attribute__((ext_vector_type(8)));
typedef __bf16 bf16x4 __attribute__((ext_vector_type(4)));
typedef float  f32x4  __attribute__((ext_vector_type(4)));
typedef float  flt4v  __attribute__((ext_vector_type(4)));
typedef int    int4v  __attribute__((ext_vector_type(4)));

#define ALPHA 0.2f
#define LOG2E 1.44269504089f
// B=8, N=2048, D=128. Inputs: h,W,a f32; adj int32. Output f32.
// Wh stored MFMA-B-fragment-native: T[b][jt(32)][kk(2)][ct(8)][lane(64)][u(8)] bf16.

// Kernel A: Wh + scores. 512 blocks x 32 rows (2 blocks/CU): all 4 waves stage,
// waves 0-1 compute 16 rows each; staging of one block overlaps compute of the other.
__global__ __launch_bounds__(256) void gat_wh(
    const float* __restrict__ h,
    const float* __restrict__ W,
    const float* __restrict__ a,
    __bf16* __restrict__ T,                  // [8][262144] bf16 tiled Wh
    float* __restrict__ ssrc,                // [8*2048] (x log2e)
    float* __restrict__ sdst)                // [8*2048] (x log2e)
{
    __shared__ __bf16 Wt[128][136];
    __shared__ float wvs[128], wvd[128];
    const int tid = threadIdx.x;
    if (tid < 128) {
        float s0 = 0.f, s1 = 0.f;
        const float* wr = W + tid * 128;
        #pragma unroll 4
        for (int e = 0; e < 128; ++e) {
            float w = wr[e];
            s0 += w * a[e];
            s1 += w * a[128 + e];
        }
        wvs[tid] = s0; wvd[tid] = s1;
    }
    #pragma unroll
    for (int it = 0; it < 8; ++it) {
        int o = (it * 256 + tid) * 8;
        flt4v v0 = *reinterpret_cast<const flt4v*>(W + o);
        flt4v v1 = *reinterpret_cast<const flt4v*>(W + o + 4);
        int d = o >> 7, e = o & 127;
        #pragma unroll
        for (int j = 0; j < 4; ++j) {
            Wt[e + j][d]     = (__bf16)v0[j];
            Wt[e + 4 + j][d] = (__bf16)v1[j];
        }
    }
    __syncthreads();
    const int wave = tid >> 6, lane = tid & 63;
    if (wave >= 2) return;                   // waves 2-3: staging only
    const int lr = lane & 15, lg = lane >> 4;
    const int row0 = blockIdx.x * 32 + wave * 16;   // flattened (b*2048+n) row base
    f32x4 acc[8];
    #pragma unroll
    for (int ct = 0; ct < 8; ++ct) acc[ct] = (f32x4){0.f, 0.f, 0.f, 0.f};
    #pragma unroll
    for (int kk = 0; kk < 4; ++kk) {
        const float* hp = h + (size_t)(row0 + lr) * 128 + kk * 32 + lg * 8;
        flt4v h0 = *reinterpret_cast<const flt4v*>(hp);
        flt4v h1 = *reinterpret_cast<const flt4v*>(hp + 4);
        bf16x8 af;
        #pragma unroll
        for (int j = 0; j < 4; ++j) { af[j] = (__bf16)h0[j]; af[4 + j] = (__bf16)h1[j]; }
        #pragma unroll
        for (int ct = 0; ct < 8; ++ct) {
            bf16x8 bf_ = *reinterpret_cast<const bf16x8*>(&Wt[ct * 16 + lr][kk * 32 + lg * 8]);
            acc[ct] = __builtin_amdgcn_mfma_f32_16x16x32_bf16(af, bf_, acc[ct], 0, 0, 0);
        }
    }
    const int b  = row0 >> 11;
    const int n0 = row0 & 2047;
    __bf16* tb = T + (size_t)b * 262144;
    const int j0t = n0 + lg * 4;
    const int jt  = j0t >> 6;
    const int kk2 = (j0t >> 5) & 1;
    const int lgp = (j0t >> 3) & 3;
    const int u0  = j0t & 7;
    #pragma unroll
    for (int ct = 0; ct < 8; ++ct) {
        bf16x4 v;
        #pragma unroll
        for (int q = 0; q < 4; ++q) v[q] = (__bf16)acc[ct][q];
        *reinterpret_cast<bf16x4*>(tb + ((jt * 2 + kk2) * 8 + ct) * 512 + lgp * 128 + lr * 8 + u0) = v;
    }
    const float* hrow = h + (size_t)(row0 + lr) * 128 + lg * 32;
    float s0 = 0.f, s1 = 0.f;
    #pragma unroll
    for (int u = 0; u < 32; u += 4) {
        flt4v hv = *reinterpret_cast<const flt4v*>(hrow + u);
        #pragma unroll
        for (int q = 0; q < 4; ++q) {
            float x = hv[q];
            s0 += x * wvs[lg * 32 + u + q];
            s1 += x * wvd[lg * 32 + u + q];
        }
    }
    s0 += __shfl_xor(s0, 16, 64); s0 += __shfl_xor(s0, 32, 64);
    s1 += __shfl_xor(s1, 16, 64); s1 += __shfl_xor(s1, 32, 64);
    if (lg == 0) {
        ssrc[row0 + lr] = s0 * LOG2E;
        sdst[row0 + lr] = s1 * LOG2E;
    }
}

// Kernel C: byte-identical to round 17 (the banked 46.7 µs version).
// 32-row tiles, 512 blocks (bid&7 = batch/XCD pin), 512 thr = 8 waves.
// P-role: wave w owns rows 4w..4w+3, coalesced adj/sdst reads, P -> A-frag-native LDS.
// MFMA-role: (kkR, cp) kk-split — no B-frag loaded twice. One barrier per interval.
__global__ __launch_bounds__(512) void gat_attn(
    const int* __restrict__ adj,                // [8][2048][2048]
    const __bf16* __restrict__ T,               // [8][262144] bf16 tiled Wh
    const float* __restrict__ ssrc,             // x log2e
    const float* __restrict__ sdst,             // x log2e
    float* __restrict__ out)                    // [8][2048][128] f32
{
    __shared__ __bf16 Pl[2][8][512];            // double-buffered A-frag P (16 KB)
    __shared__ float  lsumf[32];
    __shared__ f32x4  mbuf[4][2][2][64];        // kk=1 partial accs (16 KB)

    const int tid = threadIdx.x, w = tid >> 6, l = tid & 63;
    const int lr = l & 15, lg = l >> 4;
    const int kkR = w >> 2, cp = w & 3;         // MFMA-role
    const int b  = blockIdx.x & 7;
    const int i0 = (blockIdx.x >> 3) << 5;

    // P-role geometry
    const int prow = 4 * w + (l >> 4);          // row within 32-tile
    const int row  = i0 + prow;
    const int jc   = (l & 15) * 8;              // j-chunk within 128-j interval
    const int pt2  = (l & 15) >> 3;
    const int pkk  = ((l & 15) >> 2) & 1;
    const int plgp = (l & 15) & 3;
    const int pbuf = pt2 * 4 + (w >> 2) * 2 + pkk;
    const int pslot = (prow & 15) + plgp * 16;
    const float si = ssrc[b * 2048 + row];
    const int* arow = adj + ((size_t)b * 2048 + row) * 2048;
    const float* sd = sdst + b * 2048;
    const __bf16* tb = T + (size_t)b * 262144;

    f32x4 acc[2][2];
    #pragma unroll
    for (int g = 0; g < 2; ++g)
        #pragma unroll
        for (int c2 = 0; c2 < 2; ++c2) acc[g][c2] = (f32x4){0.f, 0.f, 0.f, 0.f};
    float lrow = 0.f;

    // ---- prologue: P(interval 0) -> Pl[0] ----
    {
        int4v a0 = *reinterpret_cast<const int4v*>(arow + jc);
        int4v a1 = *reinterpret_cast<const int4v*>(arow + jc + 4);
        flt4v s0 = *reinterpret_cast<const flt4v*>(sd + jc);
        flt4v s1 = *reinterpret_cast<const flt4v*>(sd + jc + 4);
        bf16x8 pw;
        #pragma unroll
        for (int u = 0; u < 4; ++u) {
            float e0 = si + s0[u], e1 = si + s1[u];
            e0 = fmaxf(e0, ALPHA * e0); e1 = fmaxf(e1, ALPHA * e1);
            float p0 = exp2f(e0), p1 = exp2f(e1);
            p0 = (a0[u] != 0) ? p0 : 0.f;
            p1 = (a1[u] != 0) ? p1 : 0.f;
            __bf16 pb0 = (__bf16)p0, pb1 = (__bf16)p1;
            lrow += (float)pb0 + (float)pb1;
            pw[u] = pb0; pw[4 + u] = pb1;
        }
        *reinterpret_cast<bf16x8*>(&Pl[0][pbuf][pslot * 8]) = pw;
    }
    __syncthreads();

    // ---- pipelined main loop: one barrier per interval ----
    #pragma unroll 2
    for (int iv = 0; iv < 16; ++iv) {
        const int cur = iv & 1, nxt = cur ^ 1;
        const int jt0 = iv * 2;
        // (1) next-interval adj + sdst loads (issued early)
        int4v an0 = {0,0,0,0}, an1 = {0,0,0,0};
        flt4v sn0, sn1;
        if (iv < 15) {
            const int off = (iv + 1) * 128 + jc;
            an0 = *reinterpret_cast<const int4v*>(arow + off);
            an1 = *reinterpret_cast<const int4v*>(arow + off + 4);
            sn0 = *reinterpret_cast<const flt4v*>(sd + off);
            sn1 = *reinterpret_cast<const flt4v*>(sd + off + 4);
        }
        // (2) current B-frag global loads
        const __bf16* tk0 = tb + (size_t)(((jt0 * 2 + kkR) * 8) + cp * 2) * 512 + l * 8;
        const __bf16* tk1 = tb + (size_t)((((jt0 + 1) * 2 + kkR) * 8) + cp * 2) * 512 + l * 8;
        bf16x8 b00 = *reinterpret_cast<const bf16x8*>(tk0);
        bf16x8 b01 = *reinterpret_cast<const bf16x8*>(tk0 + 512);
        bf16x8 b10 = *reinterpret_cast<const bf16x8*>(tk1);
        bf16x8 b11 = *reinterpret_cast<const bf16x8*>(tk1 + 512);
        // (3) current A-frag LDS reads
        bf16x8 a00 = *reinterpret_cast<const bf16x8*>(&Pl[cur][0 + 0 + kkR][l * 8]);
        bf16x8 a01 = *reinterpret_cast<const bf16x8*>(&Pl[cur][0 + 2 + kkR][l * 8]);
        bf16x8 a10 = *reinterpret_cast<const bf16x8*>(&Pl[cur][4 + 0 + kkR][l * 8]);
        bf16x8 a11 = *reinterpret_cast<const bf16x8*>(&Pl[cur][4 + 2 + kkR][l * 8]);
        // (4) MFMAs
        acc[0][0] = __builtin_amdgcn_mfma_f32_16x16x32_bf16(a00, b00, acc[0][0], 0, 0, 0);
        acc[0][1] = __builtin_amdgcn_mfma_f32_16x16x32_bf16(a00, b01, acc[0][1], 0, 0, 0);
        acc[1][0] = __builtin_amdgcn_mfma_f32_16x16x32_bf16(a01, b00, acc[1][0], 0, 0, 0);
        acc[1][1] = __builtin_amdgcn_mfma_f32_16x16x32_bf16(a01, b01, acc[1][1], 0, 0, 0);
        acc[0][0] = __builtin_amdgcn_mfma_f32_16x16x32_bf16(a10, b10, acc[0][0], 0, 0, 0);
        acc[0][1] = __builtin_amdgcn_mfma_f32_16x16x32_bf16(a10, b11, acc[0][1], 0, 0, 0);
        acc[1][0] = __builtin_amdgcn_mfma_f32_16x16x32_bf16(a11, b10, acc[1][0], 0, 0, 0);
        acc[1][1] = __builtin_amdgcn_mfma_f32_16x16x32_bf16(a11, b11, acc[1][1], 0, 0, 0);
        // (5) exp + ds_write next-P into other buffer
        if (iv < 15) {
            bf16x8 pw;
            #pragma unroll
            for (int u = 0; u < 4; ++u) {
                float e0 = si + sn0[u], e1 = si + sn1[u];
                e0 = fmaxf(e0, ALPHA * e0); e1 = fmaxf(e1, ALPHA * e1);
                float p0 = exp2f(e0), p1 = exp2f(e1);
                p0 = (an0[u] != 0) ? p0 : 0.f;
                p1 = (an1[u] != 0) ? p1 : 0.f;
                __bf16 pb0 = (__bf16)p0, pb1 = (__bf16)p1;
                lrow += (float)pb0 + (float)pb1;
                pw[u] = pb0; pw[4 + u] = pb1;
            }
            *reinterpret_cast<bf16x8*>(&Pl[nxt][pbuf][pslot * 8]) = pw;
        }
        // (6) single barrier
        __syncthreads();
    }

    // denominators: each row owned by one 16-lane group
    lrow += __shfl_xor(lrow, 1, 64);
    lrow += __shfl_xor(lrow, 2, 64);
    lrow += __shfl_xor(lrow, 4, 64);
    lrow += __shfl_xor(lrow, 8, 64);
    if ((l & 15) == 0) lsumf[prow] = lrow;
    // kk=1 waves publish their partial accumulators
    if (kkR == 1) {
        #pragma unroll
        for (int g = 0; g < 2; ++g)
            #pragma unroll
            for (int c2 = 0; c2 < 2; ++c2)
                mbuf[cp][g][c2][l] = acc[g][c2];
    }
    __syncthreads();
    // kk=0 waves merge + write output
    if (kkR == 0) {
        #pragma unroll
        for (int g = 0; g < 2; ++g) {
            float den[4];
            #pragma unroll
            for (int q = 0; q < 4; ++q) den[q] = lsumf[g * 16 + lg * 4 + q];
            #pragma unroll
            for (int c2 = 0; c2 < 2; ++c2) {
                f32x4 av = acc[g][c2];
                f32x4 mv = mbuf[cp][g][c2][l];
                const int col = (cp * 2 + c2) * 16 + lr;
                #pragma unroll
                for (int q = 0; q < 4; ++q) {
                    const int orow = i0 + g * 16 + lg * 4 + q;
                    out[((size_t)b * 2048 + orow) * 128 + col] = (av[q] + mv[q]) / den[q];
                }
            }
        }
    }
}

extern "C" void kernel_launch(void* const* d_in, const int* in_sizes, int n_in,
                              void* d_out, int out_size, void* d_ws, size_t ws_size,
                              hipStream_t stream)
{
    const float* h = nullptr; const int* adj = nullptr;
    const float* W = nullptr; const float* a = nullptr;
    for (int i = 0; i < n_in; ++i) {
        switch (in_sizes[i]) {
            case 2097152:  h   = (const float*)d_in[i]; break;
            case 33554432: adj = (const int*)d_in[i];   break;
            case 16384:    W   = (const float*)d_in[i]; break;
            case 256:      a   = (const float*)d_in[i]; break;
        }
    }
    if (!h || !adj || !W || !a) {
        h   = (const float*)d_in[0];
        adj = (const int*)d_in[1];
        W   = (const float*)d_in[2];
        a   = (const float*)d_in[3];
    }

    __bf16* T = (__bf16*)d_ws;                                        // 4 MB
    float* ssrc = (float*)((char*)d_ws + (size_t)4 * 1024 * 1024);    // 64 KB
    float* sdst = ssrc + 8 * 2048;                                    // 64 KB

    gat_wh<<<512, 256, 0, stream>>>(h, W, a, T, ssrc, sdst);
    gat_attn<<<512, 512, 0, stream>>>(adj, T, ssrc, sdst, (float*)d_out);
}

// Round 21
// 45.433 us; speedup vs baseline: 1.2441x; 1.0884x over previous
//
#include <hip/hip_runtime.h>
#include <hip/hip_bf16.h>

typedef __bf16 bf16x8 __attribute__((ext_vector_type(8)));
typedef __bf16 bf16x4 __attribute__((ext_vector_type(4)));
typedef float  f32x4  __attribute__((ext_vector_type(4)));
typedef float  flt4v  __attribute__((ext_vector_type(4)));
typedef int    int4v  __attribute__((ext_vector_type(4)));

#define ALPHA 0.2f
#define LOG2E 1.44269504089f
// B=8, N=2048, D=128. Inputs: h,W,a f32; adj int32. Output f32.
// Wh stored MFMA-B-fragment-native: T[b][jt(32)][kk(2)][ct(8)][lane(64)][u(8)] bf16.

// Kernel A: Wh + scores (byte-exact round-17 version: 256 blocks x 64 rows).
__global__ __launch_bounds__(256) void gat_wh(
    const float* __restrict__ h,
    const float* __restrict__ W,
    const float* __restrict__ a,
    __bf16* __restrict__ T,                  // [8][262144] bf16 tiled Wh
    float* __restrict__ ssrc,                // [8*2048] (x log2e)
    float* __restrict__ sdst)                // [8*2048] (x log2e)
{
    __shared__ __bf16 Wt[128][136];
    __shared__ float wvs[128], wvd[128];
    const int tid = threadIdx.x;
    if (tid < 128) {
        float s0 = 0.f, s1 = 0.f;
        const float* wr = W + tid * 128;
        #pragma unroll 4
        for (int e = 0; e < 128; ++e) {
            float w = wr[e];
            s0 += w * a[e];
            s1 += w * a[128 + e];
        }
        wvs[tid] = s0; wvd[tid] = s1;
    }
    #pragma unroll
    for (int it = 0; it < 8; ++it) {
        int o = (it * 256 + tid) * 8;
        flt4v v0 = *reinterpret_cast<const flt4v*>(W + o);
        flt4v v1 = *reinterpret_cast<const flt4v*>(W + o + 4);
        int d = o >> 7, e = o & 127;
        #pragma unroll
        for (int j = 0; j < 4; ++j) {
            Wt[e + j][d]     = (__bf16)v0[j];
            Wt[e + 4 + j][d] = (__bf16)v1[j];
        }
    }
    __syncthreads();
    const int wave = tid >> 6, lane = tid & 63;
    const int lr = lane & 15, lg = lane >> 4;
    const int row0 = blockIdx.x * 64 + wave * 16;
    f32x4 acc[8];
    #pragma unroll
    for (int ct = 0; ct < 8; ++ct) acc[ct] = (f32x4){0.f, 0.f, 0.f, 0.f};
    #pragma unroll
    for (int kk = 0; kk < 4; ++kk) {
        const float* hp = h + (size_t)(row0 + lr) * 128 + kk * 32 + lg * 8;
        flt4v h0 = *reinterpret_cast<const flt4v*>(hp);
        flt4v h1 = *reinterpret_cast<const flt4v*>(hp + 4);
        bf16x8 af;
        #pragma unroll
        for (int j = 0; j < 4; ++j) { af[j] = (__bf16)h0[j]; af[4 + j] = (__bf16)h1[j]; }
        #pragma unroll
        for (int ct = 0; ct < 8; ++ct) {
            bf16x8 bf_ = *reinterpret_cast<const bf16x8*>(&Wt[ct * 16 + lr][kk * 32 + lg * 8]);
            acc[ct] = __builtin_amdgcn_mfma_f32_16x16x32_bf16(af, bf_, acc[ct], 0, 0, 0);
        }
    }
    const int b  = row0 >> 11;
    const int n0 = row0 & 2047;
    __bf16* tb = T + (size_t)b * 262144;
    const int j0t = n0 + lg * 4;
    const int jt  = j0t >> 6;
    const int kk2 = (j0t >> 5) & 1;
    const int lgp = (j0t >> 3) & 3;
    const int u0  = j0t & 7;
    #pragma unroll
    for (int ct = 0; ct < 8; ++ct) {
        bf16x4 v;
        #pragma unroll
        for (int q = 0; q < 4; ++q) v[q] = (__bf16)acc[ct][q];
        *reinterpret_cast<bf16x4*>(tb + ((jt * 2 + kk2) * 8 + ct) * 512 + lgp * 128 + lr * 8 + u0) = v;
    }
    const float* hrow = h + (size_t)(row0 + lr) * 128 + lg * 32;
    float s0 = 0.f, s1 = 0.f;
    #pragma unroll
    for (int u = 0; u < 32; u += 4) {
        flt4v hv = *reinterpret_cast<const flt4v*>(hrow + u);
        #pragma unroll
        for (int q = 0; q < 4; ++q) {
            float x = hv[q];
            s0 += x * wvs[lg * 32 + u + q];
            s1 += x * wvd[lg * 32 + u + q];
        }
    }
    s0 += __shfl_xor(s0, 16, 64); s0 += __shfl_xor(s0, 32, 64);
    s1 += __shfl_xor(s1, 16, 64); s1 += __shfl_xor(s1, 32, 64);
    if (lg == 0) {
        ssrc[row0 + lr] = s0 * LOG2E;
        sdst[row0 + lr] = s1 * LOG2E;
    }
}

// Kernel C: round-17 structure with 4-DEEP Pl ring + barrier every 2nd interval.
// Read buf iv&3; write P(iv+2) into buf (iv+2)&3; barrier when (iv&1)==1.
// Everything else (roles, mappings, traffic) identical to round 17.
__global__ __launch_bounds__(512) void gat_attn(
    const int* __restrict__ adj,                // [8][2048][2048]
    const __bf16* __restrict__ T,               // [8][262144] bf16 tiled Wh
    const float* __restrict__ ssrc,             // x log2e
    const float* __restrict__ sdst,             // x log2e
    float* __restrict__ out)                    // [8][2048][128] f32
{
    __shared__ __bf16 Pl[4][8][512];            // 4-deep A-frag P ring (32 KB)
    __shared__ float  lsumf[32];
    __shared__ f32x4  mbuf[4][2][2][64];        // kk=1 partial accs (16 KB)

    const int tid = threadIdx.x, w = tid >> 6, l = tid & 63;
    const int lr = l & 15, lg = l >> 4;
    const int kkR = w >> 2, cp = w & 3;         // MFMA-role
    const int b  = blockIdx.x & 7;
    const int i0 = (blockIdx.x >> 3) << 5;

    // P-role geometry (identical to round 17)
    const int prow = 4 * w + (l >> 4);
    const int row  = i0 + prow;
    const int jc   = (l & 15) * 8;
    const int pt2  = (l & 15) >> 3;
    const int pkk  = ((l & 15) >> 2) & 1;
    const int plgp = (l & 15) & 3;
    const int pbuf = pt2 * 4 + (w >> 2) * 2 + pkk;
    const int pslot = (prow & 15) + plgp * 16;
    const float si = ssrc[b * 2048 + row];
    const int* arow = adj + ((size_t)b * 2048 + row) * 2048;
    const float* sd = sdst + b * 2048;
    const __bf16* tb = T + (size_t)b * 262144;

    f32x4 acc[2][2];
    #pragma unroll
    for (int g = 0; g < 2; ++g)
        #pragma unroll
        for (int c2 = 0; c2 < 2; ++c2) acc[g][c2] = (f32x4){0.f, 0.f, 0.f, 0.f};
    float lrow = 0.f;

    // ---- prologue: P(intervals 0 and 1) -> Pl[0], Pl[1] ----
    #pragma unroll
    for (int pv = 0; pv < 2; ++pv) {
        const int off = pv * 128 + jc;
        int4v a0 = *reinterpret_cast<const int4v*>(arow + off);
        int4v a1 = *reinterpret_cast<const int4v*>(arow + off + 4);
        flt4v s0 = *reinterpret_cast<const flt4v*>(sd + off);
        flt4v s1 = *reinterpret_cast<const flt4v*>(sd + off + 4);
        bf16x8 pw;
        #pragma unroll
        for (int u = 0; u < 4; ++u) {
            float e0 = si + s0[u], e1 = si + s1[u];
            e0 = fmaxf(e0, ALPHA * e0); e1 = fmaxf(e1, ALPHA * e1);
            float p0 = exp2f(e0), p1 = exp2f(e1);
            p0 = (a0[u] != 0) ? p0 : 0.f;
            p1 = (a1[u] != 0) ? p1 : 0.f;
            __bf16 pb0 = (__bf16)p0, pb1 = (__bf16)p1;
            lrow += (float)pb0 + (float)pb1;
            pw[u] = pb0; pw[4 + u] = pb1;
        }
        *reinterpret_cast<bf16x8*>(&Pl[pv][pbuf][pslot * 8]) = pw;
    }
    __syncthreads();

    // ---- main loop: barrier every SECOND interval (9 total) ----
    #pragma unroll 4
    for (int iv = 0; iv < 16; ++iv) {
        const int cur = iv & 3;
        const int wrt = (iv + 2) & 3;
        const int jt0 = iv * 2;
        // (1) interval iv+2 adj + sdst loads (issued early)
        int4v an0 = {0,0,0,0}, an1 = {0,0,0,0};
        flt4v sn0, sn1;
        if (iv < 14) {
            const int off = (iv + 2) * 128 + jc;
            an0 = *reinterpret_cast<const int4v*>(arow + off);
            an1 = *reinterpret_cast<const int4v*>(arow + off + 4);
            sn0 = *reinterpret_cast<const flt4v*>(sd + off);
            sn1 = *reinterpret_cast<const flt4v*>(sd + off + 4);
        }
        // (2) current B-frag global loads
        const __bf16* tk0 = tb + (size_t)(((jt0 * 2 + kkR) * 8) + cp * 2) * 512 + l * 8;
        const __bf16* tk1 = tb + (size_t)((((jt0 + 1) * 2 + kkR) * 8) + cp * 2) * 512 + l * 8;
        bf16x8 b00 = *reinterpret_cast<const bf16x8*>(tk0);
        bf16x8 b01 = *reinterpret_cast<const bf16x8*>(tk0 + 512);
        bf16x8 b10 = *reinterpret_cast<const bf16x8*>(tk1);
        bf16x8 b11 = *reinterpret_cast<const bf16x8*>(tk1 + 512);
        // (3) current A-frag LDS reads
        bf16x8 a00 = *reinterpret_cast<const bf16x8*>(&Pl[cur][0 + 0 + kkR][l * 8]);
        bf16x8 a01 = *reinterpret_cast<const bf16x8*>(&Pl[cur][0 + 2 + kkR][l * 8]);
        bf16x8 a10 = *reinterpret_cast<const bf16x8*>(&Pl[cur][4 + 0 + kkR][l * 8]);
        bf16x8 a11 = *reinterpret_cast<const bf16x8*>(&Pl[cur][4 + 2 + kkR][l * 8]);
        // (4) MFMAs
        acc[0][0] = __builtin_amdgcn_mfma_f32_16x16x32_bf16(a00, b00, acc[0][0], 0, 0, 0);
        acc[0][1] = __builtin_amdgcn_mfma_f32_16x16x32_bf16(a00, b01, acc[0][1], 0, 0, 0);
        acc[1][0] = __builtin_amdgcn_mfma_f32_16x16x32_bf16(a01, b00, acc[1][0], 0, 0, 0);
        acc[1][1] = __builtin_amdgcn_mfma_f32_16x16x32_bf16(a01, b01, acc[1][1], 0, 0, 0);
        acc[0][0] = __builtin_amdgcn_mfma_f32_16x16x32_bf16(a10, b10, acc[0][0], 0, 0, 0);
        acc[0][1] = __builtin_amdgcn_mfma_f32_16x16x32_bf16(a10, b11, acc[0][1], 0, 0, 0);
        acc[1][0] = __builtin_amdgcn_mfma_f32_16x16x32_bf16(a11, b10, acc[1][0], 0, 0, 0);
        acc[1][1] = __builtin_amdgcn_mfma_f32_16x16x32_bf16(a11, b11, acc[1][1], 0, 0, 0);
        // (5) exp + ds_write P(iv+2) into ring slot wrt
        if (iv < 14) {
            bf16x8 pw;
            #pragma unroll
            for (int u = 0; u < 4; ++u) {
                float e0 = si + sn0[u], e1 = si + sn1[u];
                e0 = fmaxf(e0, ALPHA * e0); e1 = fmaxf(e1, ALPHA * e1);
                float p0 = exp2f(e0), p1 = exp2f(e1);
                p0 = (an0[u] != 0) ? p0 : 0.f;
                p1 = (an1[u] != 0) ? p1 : 0.f;
                __bf16 pb0 = (__bf16)p0, pb1 = (__bf16)p1;
                lrow += (float)pb0 + (float)pb1;
                pw[u] = pb0; pw[4 + u] = pb1;
            }
            *reinterpret_cast<bf16x8*>(&Pl[wrt][pbuf][pslot * 8]) = pw;
        }
        // (6) barrier at the end of each pair
        if (iv & 1) __syncthreads();
    }

    // denominators: each row owned by one 16-lane group
    lrow += __shfl_xor(lrow, 1, 64);
    lrow += __shfl_xor(lrow, 2, 64);
    lrow += __shfl_xor(lrow, 4, 64);
    lrow += __shfl_xor(lrow, 8, 64);
    if ((l & 15) == 0) lsumf[prow] = lrow;
    // kk=1 waves publish their partial accumulators
    if (kkR == 1) {
        #pragma unroll
        for (int g = 0; g < 2; ++g)
            #pragma unroll
            for (int c2 = 0; c2 < 2; ++c2)
                mbuf[cp][g][c2][l] = acc[g][c2];
    }
    __syncthreads();
    // kk=0 waves merge + write output
    if (kkR == 0) {
        #pragma unroll
        for (int g = 0; g < 2; ++g) {
            float den[4];
            #pragma unroll
            for (int q = 0; q < 4; ++q) den[q] = lsumf[g * 16 + lg * 4 + q];
            #pragma unroll
            for (int c2 = 0; c2 < 2; ++c2) {
                f32x4 av = acc[g][c2];
                f32x4 mv = mbuf[cp][g][c2][l];
                const int col = (cp * 2 + c2) * 16 + lr;
                #pragma unroll
                for (int q = 0; q < 4; ++q) {
                    const int orow = i0 + g * 16 + lg * 4 + q;
                    out[((size_t)b * 2048 + orow) * 128 + col] = (av[q] + mv[q]) / den[q];
                }
            }
        }
    }
}

extern "C" void kernel_launch(void* const* d_in, const int* in_sizes, int n_in,
                              void* d_out, int out_size, void* d_ws, size_t ws_size,
                              hipStream_t stream)
{
    const float* h = nullptr; const int* adj = nullptr;
    const float* W = nullptr; const float* a = nullptr;
    for (int i = 0; i < n_in; ++i) {
        switch (in_sizes[i]) {
            case 2097152:  h   = (const float*)d_in[i]; break;
            case 33554432: adj = (const int*)d_in[i];   break;
            case 16384:    W   = (const float*)d_in[i]; break;
            case 256:      a   = (const float*)d_in[i]; break;
        }
    }
    if (!h || !adj || !W || !a) {
        h   = (const float*)d_in[0];
        adj = (const int*)d_in[1];
        W   = (const float*)d_in[2];
        a   = (const float*)d_in[3];
    }

    __bf16* T = (__bf16*)d_ws;                                        // 4 MB
    float* ssrc = (float*)((char*)d_ws + (size_t)4 * 1024 * 1024);    // 64 KB
    float* sdst = ssrc + 8 * 2048;                                    // 64 KB

    gat_wh<<<256, 256, 0, stream>>>(h, W, a, T, ssrc, sdst);
    gat_attn<<<512, 512, 0, stream>>>(adj, T, ssrc, sdst, (float*)d_out);
}